// Round 1
// baseline (1177.753 us; speedup 1.0000x reference)
//
#include <hip/hip_runtime.h>
#include <stdint.h>

#define B_TOTAL 4096
#define T_STEPS 512
#define IN_DIM 16
#define H1 5
#define H2 50
#define NCLS 20

typedef __attribute__((ext_vector_type(8))) short bf16x8;
typedef __attribute__((ext_vector_type(4))) float f32x4;

__device__ inline unsigned short f2bf(float x){
  unsigned int u = __float_as_uint(x);
  u += 0x7FFFu + ((u >> 16) & 1u);
  return (unsigned short)(u >> 16);
}
__device__ inline float bf2f(unsigned short h){ return __uint_as_float(((unsigned int)h) << 16); }
__device__ inline float sigm(float x){ return 1.0f/(1.0f + __expf(-x)); }
__device__ inline float tanh_(float x){ return 1.0f - 2.0f/(__expf(2.0f*x) + 1.0f); }

// ---------------- LSTM layer 1 ----------------
// grid 256 (batch tiles of 16), block 256 (4 waves). Wave w handles gate-type w.
// A (16 x 32): cols [x(16) | h1(5) | pad]; N=64 (4 types x 16-padded cells).
__global__ __launch_bounds__(256) void lstm1_kernel(
    const float* __restrict__ x, const float* __restrict__ w_ih1,
    const float* __restrict__ w_hh1, const float* __restrict__ b_ih1,
    const float* __restrict__ b_hh1, float* __restrict__ h1T)
{
  const int tid  = threadIdx.x;
  const int lane = tid & 63;
  const int wave = tid >> 6;      // 0..3 = gate type
  const int l15  = lane & 15;
  const int quad = lane >> 4;
  const int b0   = blockIdx.x * 16;

  __shared__ __align__(16) unsigned short a_hi[16*40];
  __shared__ __align__(16) unsigned short a_lo[16*40];
  __shared__ float a_g[64*17];

  // B fragment preload (loop-invariant): split hi/lo bf16
  bf16x8 bh, bl;
  float biasv = 0.f;
  {
    int c = l15;
    bool valid = c < H1;
    int grow = wave*H1 + c;
    for (int j=0;j<8;j++){
      int k = quad*8 + j;
      float w = 0.f;
      if (valid){
        if (k < IN_DIM)           w = w_ih1[grow*IN_DIM + k];
        else if (k < IN_DIM+H1)   w = w_hh1[grow*H1 + (k-IN_DIM)];
      }
      unsigned short h = f2bf(w);
      unsigned short l = f2bf(w - bf2f(h));
      bh[j] = (short)h; bl[j] = (short)l;
    }
    if (valid) biasv = b_ih1[grow] + b_hh1[grow];
  }

  for (int i=tid; i<16*40; i+=256){ a_hi[i]=0; a_lo[i]=0; }
  __syncthreads();

  // stage x(0): wave 0 loads 16 batches x 16 dims as float4
  const int xi  = l15;   // batch within tile
  const int xd4 = quad;  // dword-quad of the 16 dims
  float4 xv = make_float4(0,0,0,0);
  if (tid < 64){
    xv = *(const float4*)&x[(size_t)(b0+xi)*T_STEPS*IN_DIM + 0*IN_DIM + xd4*4];
    for (int q=0;q<4;q++){
      float v = (&xv.x)[q];
      unsigned short h = f2bf(v), l = f2bf(v - bf2f(h));
      a_hi[xi*40 + xd4*4 + q] = h;
      a_lo[xi*40 + xd4*4 + q] = l;
    }
  }

  float c1 = 0.f;
  const int uc = tid >> 4;   // cell (update threads: tid<80)
  const int ub = tid & 15;   // batch

  for (int t=0; t<T_STEPS; ++t){
    __syncthreads();  // barA: a_sm ready
    bf16x8 ah = *(const bf16x8*)&a_hi[l15*40 + quad*8];
    bf16x8 al = *(const bf16x8*)&a_lo[l15*40 + quad*8];
    f32x4 acc = {biasv, biasv, biasv, biasv};
    acc = __builtin_amdgcn_mfma_f32_16x16x32_bf16(ah, bh, acc, 0,0,0);
    acc = __builtin_amdgcn_mfma_f32_16x16x32_bf16(al, bh, acc, 0,0,0);
    acc = __builtin_amdgcn_mfma_f32_16x16x32_bf16(ah, bl, acc, 0,0,0);

    float4 xn = make_float4(0,0,0,0);
    if (tid < 64 && t+1 < T_STEPS){
      xn = *(const float4*)&x[(size_t)(b0+xi)*T_STEPS*IN_DIM + (size_t)(t+1)*IN_DIM + xd4*4];
    }

    { // activation (uniform per wave) + write gates
      int gate = wave*16 + l15;
      for (int r=0;r<4;r++){
        float v = acc[r];
        v = (wave==2) ? tanh_(v) : sigm(v);
        a_g[gate*17 + quad*4 + r] = v;
      }
    }
    __syncthreads();  // barB: gates ready, A-reads done
    if (tid < 80){
      float gi = a_g[( 0+uc)*17 + ub];
      float gf = a_g[(16+uc)*17 + ub];
      float gg = a_g[(32+uc)*17 + ub];
      float go = a_g[(48+uc)*17 + ub];
      c1 = gf*c1 + gi*gg;
      float h = go * tanh_(c1);
      unsigned short hh = f2bf(h), hl = f2bf(h - bf2f(hh));
      a_hi[ub*40 + IN_DIM + uc] = hh;
      a_lo[ub*40 + IN_DIM + uc] = hl;
      h1T[((size_t)t*H1 + uc)*B_TOTAL + b0 + ub] = h;
    }
    if (tid < 64){
      for (int q=0;q<4;q++){
        float v = (&xn.x)[q];
        unsigned short h = f2bf(v), l = f2bf(v - bf2f(h));
        a_hi[xi*40 + xd4*4 + q] = h;
        a_lo[xi*40 + xd4*4 + q] = l;
      }
    }
  }
}

// ---------------- LSTM layer 2 + FC ----------------
// grid 256, block 512 (8 waves). N=256 (4 types x 64-padded cells), 2 tiles/wave.
// A (16 x 64): cols [h2(50) | h1(5) | pad]. K-tiles: 2.
__global__ __launch_bounds__(512) void lstm2_kernel(
    const float* __restrict__ h1T, const float* __restrict__ w_ih2,
    const float* __restrict__ w_hh2, const float* __restrict__ b_ih2,
    const float* __restrict__ b_hh2, const float* __restrict__ fc_w,
    const float* __restrict__ fc_b, float* __restrict__ out)
{
  const int tid  = threadIdx.x;
  const int lane = tid & 63;
  const int wave = tid >> 6;    // 0..7
  const int l15  = lane & 15;
  const int quad = lane >> 4;
  const int b0   = blockIdx.x * 16;

  __shared__ __align__(16) unsigned short a_hi[16*72];
  __shared__ __align__(16) unsigned short a_lo[16*72];
  __shared__ float a_g[256*17];
  __shared__ float h2f[50*17];

  bf16x8 bh[2][2], bl[2][2];
  float biasv[2];
  for (int tl=0; tl<2; ++tl){
    int tn   = wave*2 + tl;        // 0..15
    int type = tn >> 2;            // 0..3
    int cg   = (tn & 3)*16 + l15;  // cell within type block (0..63)
    bool valid = cg < H2;
    int grow = type*H2 + cg;
    for (int kt=0; kt<2; ++kt){
      for (int j=0;j<8;j++){
        int k = kt*32 + quad*8 + j;
        float w = 0.f;
        if (valid){
          if (k < H2)            w = w_hh2[grow*H2 + k];
          else if (k < H2+H1)    w = w_ih2[grow*H1 + (k-H2)];
        }
        unsigned short h = f2bf(w), l = f2bf(w - bf2f(h));
        bh[tl][kt][j] = (short)h; bl[tl][kt][j] = (short)l;
      }
    }
    biasv[tl] = valid ? (b_ih2[grow] + b_hh2[grow]) : 0.f;
  }

  for (int i=tid; i<16*72; i+=512){ a_hi[i]=0; a_lo[i]=0; }
  __syncthreads();

  const int hc = tid >> 4;  // h1 cell (tid<80)
  const int hb = tid & 15;  // batch
  if (tid < 80){
    float h1v = h1T[(size_t)hc*B_TOTAL + b0 + hb];  // t=0
    unsigned short h = f2bf(h1v), l = f2bf(h1v - bf2f(h));
    a_hi[hb*72 + H2 + hc] = h;
    a_lo[hb*72 + H2 + hc] = l;
  }

  float c2[2] = {0.f, 0.f};
  const int type = wave >> 1;  // uniform per wave

  for (int t=0; t<T_STEPS; ++t){
    __syncthreads(); // barA
    bf16x8 ah[2], al[2];
    for (int kt=0; kt<2; ++kt){
      ah[kt] = *(const bf16x8*)&a_hi[l15*72 + kt*32 + quad*8];
      al[kt] = *(const bf16x8*)&a_lo[l15*72 + kt*32 + quad*8];
    }
    f32x4 acc[2];
    for (int tl=0; tl<2; ++tl){
      f32x4 a = {biasv[tl],biasv[tl],biasv[tl],biasv[tl]};
      for (int kt=0; kt<2; ++kt){
        a = __builtin_amdgcn_mfma_f32_16x16x32_bf16(ah[kt], bh[tl][kt], a, 0,0,0);
        a = __builtin_amdgcn_mfma_f32_16x16x32_bf16(al[kt], bh[tl][kt], a, 0,0,0);
        a = __builtin_amdgcn_mfma_f32_16x16x32_bf16(ah[kt], bl[tl][kt], a, 0,0,0);
      }
      acc[tl] = a;
    }
    float h1n = 0.f;
    if (tid < 80 && t+1 < T_STEPS)
      h1n = h1T[((size_t)(t+1)*H1 + hc)*B_TOTAL + b0 + hb];

    for (int tl=0; tl<2; ++tl){
      int gate = (wave*2 + tl)*16 + l15; // 0..255
      for (int r=0;r<4;r++){
        float v = acc[tl][r];
        v = (type==2) ? tanh_(v) : sigm(v);
        a_g[gate*17 + quad*4 + r] = v;
      }
    }
    __syncthreads(); // barB
    for (int u=0; u<2; ++u){
      int idx = tid + u*512;
      if (idx < 800){
        int c = idx >> 4, b = idx & 15;
        float gi = a_g[(  0+c)*17 + b];
        float gf = a_g[( 64+c)*17 + b];
        float gg = a_g[(128+c)*17 + b];
        float go = a_g[(192+c)*17 + b];
        c2[u] = gf*c2[u] + gi*gg;
        float h = go * tanh_(c2[u]);
        unsigned short hh = f2bf(h), hl = f2bf(h - bf2f(hh));
        a_hi[b*72 + c] = hh;
        a_lo[b*72 + c] = hl;
        if (t == T_STEPS-1){
          out[(size_t)B_TOTAL*NCLS + (size_t)(b0+b)*H2 + c] = h;
          h2f[c*17 + b] = h;
        }
      }
    }
    if (tid < 80){
      unsigned short h = f2bf(h1n), l = f2bf(h1n - bf2f(h));
      a_hi[hb*72 + H2 + hc] = h;
      a_lo[hb*72 + H2 + hc] = l;
    }
  }
  __syncthreads();
  // fused FC epilogue: 16 batches x 20 outputs
  if (tid < 320){
    int o = tid % 20, b = tid / 20;
    float s = fc_b[o];
    for (int k=0;k<H2;k++) s += fc_w[o*H2+k] * h2f[k*17 + b];
    out[(size_t)(b0+b)*NCLS + o] = s;
  }
}

extern "C" void kernel_launch(void* const* d_in, const int* in_sizes, int n_in,
                              void* d_out, int out_size, void* d_ws, size_t ws_size,
                              hipStream_t stream) {
  const float* x     = (const float*)d_in[0];
  const float* w_ih1 = (const float*)d_in[1];
  const float* w_hh1 = (const float*)d_in[2];
  const float* b_ih1 = (const float*)d_in[3];
  const float* b_hh1 = (const float*)d_in[4];
  const float* w_ih2 = (const float*)d_in[5];
  const float* w_hh2 = (const float*)d_in[6];
  const float* b_ih2 = (const float*)d_in[7];
  const float* b_hh2 = (const float*)d_in[8];
  const float* fc_w  = (const float*)d_in[9];
  const float* fc_b  = (const float*)d_in[10];
  float* h1T = (float*)d_ws;   // (T, H1, B) fp32 = 40 MiB
  float* out = (float*)d_out;

  lstm1_kernel<<<dim3(B_TOTAL/16), dim3(256), 0, stream>>>(x, w_ih1, w_hh1, b_ih1, b_hh1, h1T);
  lstm2_kernel<<<dim3(B_TOTAL/16), dim3(512), 0, stream>>>(h1T, w_ih2, w_hh2, b_ih2, b_hh2, fc_w, fc_b, out);
}

// Round 2
// 733.464 us; speedup vs baseline: 1.6057x; 1.6057x over previous
//
#include <hip/hip_runtime.h>
#include <stdint.h>

#define B_TOTAL 4096
#define T_STEPS 512
#define IN_DIM 16
#define H1 5
#define H2 50
#define NCLS 20

typedef __attribute__((ext_vector_type(8))) short bf16x8;
typedef __attribute__((ext_vector_type(4))) float f32x4;

__device__ inline unsigned short f2bf(float x){
  unsigned int u = __float_as_uint(x);
  u += 0x7FFFu + ((u >> 16) & 1u);
  return (unsigned short)(u >> 16);
}
__device__ inline float bf2f(unsigned short h){ return __uint_as_float(((unsigned int)h) << 16); }

#define LOG2E 1.44269504f
__device__ inline float sigm(float x){
  float e = __builtin_amdgcn_exp2f(-LOG2E * x);
  return __builtin_amdgcn_rcpf(1.0f + e);
}
__device__ inline float tanh_(float x){
  float e = __builtin_amdgcn_exp2f((2.0f*LOG2E) * x);
  float r = __builtin_amdgcn_rcpf(1.0f + e);
  return fmaf(-2.0f, r, 1.0f);
}

// Fused 2-layer LSTM + FC. grid 256 (16-batch tiles), block 320 (5 waves).
// Waves 0..3: lstm2, each owns a 16-cell group; per step 4 gate-type MFMA
//   chains over the same columns -> all 4 gates per (cell,batch) in-register,
//   no gate transpose, no gate LDS.
// Wave 4: lstm1 (5 cells padded to 16 cols), one timestep AHEAD of lstm2;
//   hands h1(t) to lstm2 through the double-buffered A2 LDS.
// One __syncthreads per superstep (513 total).
__global__ __launch_bounds__(320) void lstm_fused_kernel(
    const float* __restrict__ x,
    const float* __restrict__ w_ih1, const float* __restrict__ w_hh1,
    const float* __restrict__ b_ih1, const float* __restrict__ b_hh1,
    const float* __restrict__ w_ih2, const float* __restrict__ w_hh2,
    const float* __restrict__ b_ih2, const float* __restrict__ b_hh2,
    const float* __restrict__ fc_w, const float* __restrict__ fc_b,
    float* __restrict__ out)
{
  const int tid  = threadIdx.x;
  const int lane = tid & 63;
  const int wave = tid >> 6;      // 0..3 lstm2 cell-groups, 4 = lstm1
  const int l15  = lane & 15;
  const int quad = lane >> 4;
  const int b0   = blockIdx.x * 16;

  // A1: 16 batches x [x(16)|h1(5)|pad] = 40 shorts/row, double buffered
  // A2: 16 batches x [h2(50)|h1(5)|pad] = 72 shorts/row, double buffered
  __shared__ __align__(16) unsigned short a1_hi[2][16*40];
  __shared__ __align__(16) unsigned short a1_lo[2][16*40];
  __shared__ __align__(16) unsigned short a2_hi[2][16*72];
  __shared__ __align__(16) unsigned short a2_lo[2][16*72];
  __shared__ float h2f[16*52];

  bf16x8 Bh[4][2], Bl[4][2];
  float bias[4];
  float cst[4] = {0.f, 0.f, 0.f, 0.f};

  if (wave == 4) {
    // lstm1 weights: B[cell=l15][k], k = quad*8+j, cols [x(16)|h1(5)|pad]
    bool valid = l15 < H1;
#pragma unroll
    for (int tt=0; tt<4; ++tt){
      int grow = tt*H1 + l15;
#pragma unroll
      for (int j=0;j<8;j++){
        int k = quad*8 + j;
        float w = 0.f;
        if (valid){
          if (k < IN_DIM)          w = w_ih1[grow*IN_DIM + k];
          else if (k < IN_DIM+H1)  w = w_hh1[grow*H1 + (k-IN_DIM)];
        }
        unsigned short h = f2bf(w), l = f2bf(w - bf2f(h));
        Bh[tt][0][j] = (short)h; Bl[tt][0][j] = (short)l;
        Bh[tt][1][j] = 0;        Bl[tt][1][j] = 0;
      }
      bias[tt] = valid ? (b_ih1[grow] + b_hh1[grow]) : 0.f;
    }
  } else {
    // lstm2 weights: cell group cg = wave*16+l15, cols [h2(50)|h1(5)|pad]
    int cg = wave*16 + l15;
    bool valid = cg < H2;
#pragma unroll
    for (int tt=0; tt<4; ++tt){
      int grow = tt*H2 + cg;
#pragma unroll
      for (int kt=0; kt<2; ++kt){
#pragma unroll
        for (int j=0;j<8;j++){
          int k = kt*32 + quad*8 + j;
          float w = 0.f;
          if (valid){
            if (k < H2)          w = w_hh2[grow*H2 + k];
            else if (k < H2+H1)  w = w_ih2[grow*H1 + (k-H2)];
          }
          unsigned short h = f2bf(w), l = f2bf(w - bf2f(h));
          Bh[tt][kt][j] = (short)h; Bl[tt][kt][j] = (short)l;
        }
      }
      bias[tt] = valid ? (b_ih2[grow] + b_hh2[grow]) : 0.f;
    }
  }

  // zero both A buffers (pads must stay zero)
  {
    unsigned short* p;
    p = &a1_hi[0][0]; for (int i=tid;i<2*16*40;i+=320) p[i]=0;
    p = &a1_lo[0][0]; for (int i=tid;i<2*16*40;i+=320) p[i]=0;
    p = &a2_hi[0][0]; for (int i=tid;i<2*16*72;i+=320) p[i]=0;
    p = &a2_lo[0][0]; for (int i=tid;i<2*16*72;i+=320) p[i]=0;
  }

  // x staging lane map (wave 4): batch = lane>>2, dims d0..d0+3
  const int xb = lane >> 2;
  const int xd = (lane & 3) * 4;
  float4 xa = make_float4(0,0,0,0);   // x(t+1), to store this superstep
  if (wave == 4) {
    // stage x(0) directly into buf0, prefetch x(1)
    float4 x0 = *(const float4*)&x[((size_t)(b0+xb)*T_STEPS + 0)*IN_DIM + xd];
    uint2 uh, ul;
    unsigned short h0=f2bf(x0.x), h1v=f2bf(x0.y), h2v=f2bf(x0.z), h3=f2bf(x0.w);
    unsigned short l0=f2bf(x0.x-bf2f(h0)), l1=f2bf(x0.y-bf2f(h1v)),
                   l2=f2bf(x0.z-bf2f(h2v)), l3=f2bf(x0.w-bf2f(h3));
    uh.x = (unsigned)h0 | ((unsigned)h1v<<16); uh.y = (unsigned)h2v | ((unsigned)h3<<16);
    ul.x = (unsigned)l0 | ((unsigned)l1<<16);  ul.y = (unsigned)l2 | ((unsigned)l3<<16);
    *(uint2*)&a1_hi[0][xb*40 + xd] = uh;
    *(uint2*)&a1_lo[0][xb*40 + xd] = ul;
    xa = *(const float4*)&x[((size_t)(b0+xb)*T_STEPS + 1)*IN_DIM + xd];
  }

  for (int t=0; t<=T_STEPS; ++t){
    __syncthreads();
    const int rd = t & 1, wr = rd ^ 1;

    if (wave == 4){
      if (t < T_STEPS){
        // prefetch x(t+2)
        float4 xn = make_float4(0,0,0,0);
        if (t+2 < T_STEPS)
          xn = *(const float4*)&x[((size_t)(b0+xb)*T_STEPS + (t+2))*IN_DIM + xd];

        bf16x8 ah = *(const bf16x8*)&a1_hi[rd][l15*40 + quad*8];
        bf16x8 al = *(const bf16x8*)&a1_lo[rd][l15*40 + quad*8];
        f32x4 acc[4];
#pragma unroll
        for (int tt=0; tt<4; ++tt){
          f32x4 a = {bias[tt], bias[tt], bias[tt], bias[tt]};
          a = __builtin_amdgcn_mfma_f32_16x16x32_bf16(ah, Bh[tt][0], a, 0,0,0);
          a = __builtin_amdgcn_mfma_f32_16x16x32_bf16(al, Bh[tt][0], a, 0,0,0);
          a = __builtin_amdgcn_mfma_f32_16x16x32_bf16(ah, Bl[tt][0], a, 0,0,0);
          acc[tt] = a;
        }
#pragma unroll
        for (int r=0;r<4;r++){
          float gi = sigm(acc[0][r]);
          float gf = sigm(acc[1][r]);
          float gg = tanh_(acc[2][r]);
          float go = sigm(acc[3][r]);
          cst[r] = gf*cst[r] + gi*gg;
          float h = go * tanh_(cst[r]);
          unsigned short hh = f2bf(h), hl = f2bf(h - bf2f(hh));
          int bb = quad*4 + r;
          if (l15 < H1){
            a1_hi[wr][bb*40 + IN_DIM + l15] = hh;
            a1_lo[wr][bb*40 + IN_DIM + l15] = hl;
            a2_hi[wr][bb*72 + H2 + l15] = hh;
            a2_lo[wr][bb*72 + H2 + l15] = hl;
          }
        }
        // store x(t+1) into wr buffer; advance prefetch reg
        if (t+1 < T_STEPS){
          unsigned short h0=f2bf(xa.x), h1v=f2bf(xa.y), h2v=f2bf(xa.z), h3=f2bf(xa.w);
          unsigned short l0=f2bf(xa.x-bf2f(h0)), l1=f2bf(xa.y-bf2f(h1v)),
                         l2=f2bf(xa.z-bf2f(h2v)), l3=f2bf(xa.w-bf2f(h3));
          uint2 uh, ul;
          uh.x = (unsigned)h0 | ((unsigned)h1v<<16); uh.y = (unsigned)h2v | ((unsigned)h3<<16);
          ul.x = (unsigned)l0 | ((unsigned)l1<<16);  ul.y = (unsigned)l2 | ((unsigned)l3<<16);
          *(uint2*)&a1_hi[wr][xb*40 + xd] = uh;
          *(uint2*)&a1_lo[wr][xb*40 + xd] = ul;
        }
        xa = xn;
      }
    } else {
      if (t >= 1){
        const int cg = wave*16 + l15;
        bf16x8 ah0 = *(const bf16x8*)&a2_hi[rd][l15*72 +  0 + quad*8];
        bf16x8 al0 = *(const bf16x8*)&a2_lo[rd][l15*72 +  0 + quad*8];
        bf16x8 ah1 = *(const bf16x8*)&a2_hi[rd][l15*72 + 32 + quad*8];
        bf16x8 al1 = *(const bf16x8*)&a2_lo[rd][l15*72 + 32 + quad*8];
        f32x4 acc[4];
#pragma unroll
        for (int tt=0; tt<4; ++tt){
          f32x4 a = {bias[tt], bias[tt], bias[tt], bias[tt]};
          a = __builtin_amdgcn_mfma_f32_16x16x32_bf16(ah0, Bh[tt][0], a, 0,0,0);
          a = __builtin_amdgcn_mfma_f32_16x16x32_bf16(al0, Bh[tt][0], a, 0,0,0);
          a = __builtin_amdgcn_mfma_f32_16x16x32_bf16(ah0, Bl[tt][0], a, 0,0,0);
          a = __builtin_amdgcn_mfma_f32_16x16x32_bf16(ah1, Bh[tt][1], a, 0,0,0);
          a = __builtin_amdgcn_mfma_f32_16x16x32_bf16(al1, Bh[tt][1], a, 0,0,0);
          a = __builtin_amdgcn_mfma_f32_16x16x32_bf16(ah1, Bl[tt][1], a, 0,0,0);
          acc[tt] = a;
        }
#pragma unroll
        for (int r=0;r<4;r++){
          float gi = sigm(acc[0][r]);
          float gf = sigm(acc[1][r]);
          float gg = tanh_(acc[2][r]);
          float go = sigm(acc[3][r]);
          cst[r] = gf*cst[r] + gi*gg;
          float h = go * tanh_(cst[r]);
          unsigned short hh = f2bf(h), hl = f2bf(h - bf2f(hh));
          int bb = quad*4 + r;
          if (cg < H2){
            a2_hi[wr][bb*72 + cg] = hh;
            a2_lo[wr][bb*72 + cg] = hl;
            if (t == T_STEPS){
              out[(size_t)B_TOTAL*NCLS + (size_t)(b0+bb)*H2 + cg] = h;
              h2f[bb*52 + cg] = h;
            }
          }
        }
      }
    }
  }

  __syncthreads();
  // fused FC: 16 batches x 20 outputs = 320 threads exactly
  {
    int b = tid / 20, o = tid % 20;
    float s = fc_b[o];
#pragma unroll 10
    for (int k=0;k<H2;k++) s += fc_w[o*H2+k] * h2f[b*52+k];
    out[(size_t)(b0+b)*NCLS + o] = s;
  }
}

extern "C" void kernel_launch(void* const* d_in, const int* in_sizes, int n_in,
                              void* d_out, int out_size, void* d_ws, size_t ws_size,
                              hipStream_t stream) {
  const float* x     = (const float*)d_in[0];
  const float* w_ih1 = (const float*)d_in[1];
  const float* w_hh1 = (const float*)d_in[2];
  const float* b_ih1 = (const float*)d_in[3];
  const float* b_hh1 = (const float*)d_in[4];
  const float* w_ih2 = (const float*)d_in[5];
  const float* w_hh2 = (const float*)d_in[6];
  const float* b_ih2 = (const float*)d_in[7];
  const float* b_hh2 = (const float*)d_in[8];
  const float* fc_w  = (const float*)d_in[9];
  const float* fc_b  = (const float*)d_in[10];
  float* out = (float*)d_out;

  lstm_fused_kernel<<<dim3(B_TOTAL/16), dim3(320), 0, stream>>>(
      x, w_ih1, w_hh1, b_ih1, b_hh1, w_ih2, w_hh2, b_ih2, b_hh2, fc_w, fc_b, out);
}